// Round 3
// baseline (172.961 us; speedup 1.0000x reference)
//
#include <hip/hip_runtime.h>
#include <cstdint>
#include <cfloat>
#include <math.h>

// Problem constants (match reference)
#define BB 16
#define SS 64
#define VV 50257
#define PP 64

#define NT 256          // threads per block
#define BINS 2048       // key histogram bins (top 11 bits of ordered key)
#define CAP 1536        // candidate buffer capacity
#define BMW 1572        // bitmap words: ceil(50257/32)=1571, padded
#define KCAP 128        // kept (top-k survivors) capacity
#define BCAP 512        // kth-bin member list capacity
#define T0S 7.5f        // static candidate threshold (scaled units; kth ~ 11.6)

// monotone float->uint key (increasing)
__device__ __forceinline__ uint32_t fkey(float f) {
    uint32_t u = __float_as_uint(f);
    return u ^ ((uint32_t)((int32_t)u >> 31) | 0x80000000u);
}
__device__ __forceinline__ float key2f(uint32_t u) {
    uint32_t b = (u & 0x80000000u) ? (u ^ 0x80000000u) : ~u;
    return __uint_as_float(b);
}

__global__ __launch_bounds__(NT)
void sch_kernel(const float* __restrict__ logits,
                const int* __restrict__ prev,
                float* __restrict__ out)
{
    const int r   = blockIdx.x;            // row in [0, B*S)
    const int b   = r / SS;
    const int s   = r % SS;
    const int tid = threadIdx.x;
    const float* row  = logits + (size_t)r * VV;
    float*       orow = out    + (size_t)r * VV;

    __shared__ uint32_t s_bm[BMW];
    __shared__ float    s_cv[CAP];
    __shared__ int      s_ci[CAP];
    __shared__ uint32_t s_hist[BINS];
    __shared__ uint32_t s_scan[NT];
    __shared__ int      s_ptok[PP];
    __shared__ float    s_pval[PP];   // f32 scaled penalized value (selection only)
    __shared__ float    s_praw[PP];   // raw f32 logit of penalized token (this batch)
    __shared__ int      s_pneg[PP];   // all_neg flag
    __shared__ float    s_binv[BCAP];
    __shared__ double   s_v64[KCAP];  // f64 decision values of kept candidates
    __shared__ int      s_ki[KCAP];
    __shared__ float    s_kof[KCAP];  // final f32 log-probs (sorted order)
    __shared__ int   s_cnt, s_b50, s_need, s_cntb, s_k50, s_kp;
    __shared__ float s_kth, s_rc;

    // ---------------- phase 0: repetition-penalty setup ----------------
    for (int i = tid; i < BMW; i += NT) s_bm[i] = 0u;
    __syncthreads();
    if (tid < PP) {
        int tok = prev[s * PP + tid];
        bool allneg = true;
        float gown = 0.f;
        #pragma unroll 1
        for (int b2 = 0; b2 < BB; ++b2) {
            float g = logits[((size_t)b2 * SS + s) * (size_t)VV + tok];
            allneg = allneg && (g < 0.f);
            if (b2 == b) gown = g;
        }
        float pen = allneg ? (gown * 1.2f) : (gown / 1.2f);
        s_ptok[tid] = tok;
        s_pval[tid] = pen / 0.8f;          // f32 path: candidate selection only
        s_praw[tid] = gown;
        s_pneg[tid] = allneg ? 1 : 0;
        atomicOr(&s_bm[tok >> 5], 1u << (tok & 31));
    }
    if (tid == 0) s_cnt = 0;
    __syncthreads();

    // ---------------- streaming helpers (f32, selection only) ----------------
    const int mis   = (int)(((size_t)row >> 2) & 3);
    const int head  = (4 - mis) & 3;
    const int nq    = (VV - head) >> 2;
    const int ttail = head + (nq << 2);

    auto proc = [&](int t, float raw, bool doHist, float thr) {
        float v = raw / 0.8f;
        uint32_t w = s_bm[t >> 5];
        if ((w >> (t & 31)) & 1u) {
            #pragma unroll 1
            for (int j = 0; j < PP; ++j)
                if (s_ptok[j] == t) { v = s_pval[j]; break; }
        }
        if (!doHist) {
            if (v >= thr) {
                int pos = atomicAdd(&s_cnt, 1);
                if (pos < CAP) { s_cv[pos] = v; s_ci[pos] = t; }
            }
        } else {
            atomicAdd(&s_hist[fkey(v) >> 21], 1u);
        }
    };
    auto stream = [&](bool doHist, float thr) {
        if (tid < head) proc(tid, row[tid], doHist, thr);
        for (int q = tid; q < nq; q += NT) {
            int t = head + (q << 2);
            float4 f = *reinterpret_cast<const float4*>(row + t);
            proc(t + 0, f.x, doHist, thr);
            proc(t + 1, f.y, doHist, thr);
            proc(t + 2, f.z, doHist, thr);
            proc(t + 3, f.w, doHist, thr);
        }
        if (ttail + tid < VV) proc(ttail + tid, row[ttail + tid], doHist, thr);
    };
    auto findB50 = [&](int target) {
        __syncthreads();
        const int per = BINS / NT;
        int base = tid * per;
        uint32_t loc = 0;
        for (int k = 0; k < per; ++k) loc += s_hist[base + k];
        s_scan[tid] = loc;
        __syncthreads();
        for (int off = 1; off < NT; off <<= 1) {
            uint32_t add = (tid + off < NT) ? s_scan[tid + off] : 0u;
            __syncthreads();
            s_scan[tid] += add;
            __syncthreads();
        }
        uint32_t run = (tid + 1 < NT) ? s_scan[tid + 1] : 0u;
        for (int k = per - 1; k >= 0; --k) {
            uint32_t h = s_hist[base + k];
            uint32_t run2 = run + h;
            if (run < (uint32_t)target && run2 >= (uint32_t)target) {
                s_b50 = base + k;
                s_need = target - (int)run;
            }
            run = run2;
        }
        __syncthreads();
    };

    // ---------------- phase 1: collect candidates (1 global read) ----------------
    stream(false, T0S);
    __syncthreads();
    int cnt = s_cnt;
    bool okc = (cnt >= 50 && cnt <= CAP);
    if (!okc) {
        for (int i = tid; i < BINS; i += NT) s_hist[i] = 0u;
        __syncthreads();
        stream(true, 0.f);
        findB50(50);
        float thrF = key2f((uint32_t)s_b50 << 21);
        if (tid == 0) s_cnt = 0;
        __syncthreads();
        stream(false, thrF);
        __syncthreads();
        cnt = s_cnt;
    }
    const int cntc = min(cnt, CAP);

    // ---------------- phase 2: f32 kth (50th largest) among candidates ----------------
    for (int i = tid; i < BINS; i += NT) s_hist[i] = 0u;
    if (tid == 0) { s_cntb = 0; s_kth = -FLT_MAX; }
    __syncthreads();
    for (int i = tid; i < cntc; i += NT)
        atomicAdd(&s_hist[fkey(s_cv[i]) >> 21], 1u);
    findB50(50);
    const int b50 = s_b50, need = s_need;
    for (int i = tid; i < cntc; i += NT) {
        if ((int)(fkey(s_cv[i]) >> 21) == b50) {
            int p = atomicAdd(&s_cntb, 1);
            if (p < BCAP) s_binv[p] = s_cv[i];
        }
    }
    __syncthreads();
    const int cb = min(s_cntb, BCAP);
    // rank-count over ALL bin members (grid-stride: cb may exceed NT)
    for (int i = tid; i < cb; i += NT) {
        float vi = s_binv[i];
        int gt = 0, ge = 0;
        for (int j = 0; j < cb; ++j) {
            float vj = s_binv[j];
            gt += (vj > vi);
            ge += (vj >= vi);
        }
        if (gt < need && ge >= need) s_kth = vi;   // benign race: identical value
    }
    if (tid == 0) s_k50 = 0;
    __syncthreads();
    const float kth = s_kth;

    // ---------------- phase 3: gather kept (margin below kth32), build f64 values ----
    // {v32 >= kth32} provably contains the f64-top-50 (monotone rounding);
    // margin guards 1-ulp cross-precision inversions between penalized/plain.
    const float gthr = kth - 1e-4f;
    for (int i = tid; i < cntc; i += NT) {
        if (s_cv[i] >= gthr) {
            int p = atomicAdd(&s_k50, 1);
            if (p < KCAP) {
                int tok = s_ci[i];
                double v64;
                uint32_t w = s_bm[tok >> 5];
                bool pn = (w >> (tok & 31)) & 1u;
                int pj = -1;
                if (pn) {
                    #pragma unroll 1
                    for (int j = 0; j < PP; ++j)
                        if (s_ptok[j] == tok) { pj = j; break; }
                }
                if (pj >= 0) {
                    double g = (double)s_praw[pj];
                    double pen = s_pneg[pj] ? (g * 1.2) : (g / 1.2);
                    v64 = pen / 0.8;
                } else {
                    v64 = (double)row[tok] / 0.8;     // L2-hot scalar reread
                }
                s_v64[p] = v64;
                s_ki[p]  = tok;
            }
        }
    }
    __syncthreads();
    const int k50c = min(s_k50, KCAP);
    for (int i = k50c + tid; i < KCAP; i += NT) {
        s_v64[i] = -1e300;
        s_ki[i]  = (1 << 30) + i;     // distinct, sinks to bottom
    }
    __syncthreads();

    // bitonic sort, 128 slots: descending v64, tie -> ascending token idx
    // (mirrors np stable argsort; deterministic regardless of atomic order)
    for (int k = 2; k <= KCAP; k <<= 1) {
        for (int j = k >> 1; j > 0; j >>= 1) {
            if (tid < KCAP) {
                int i = tid, l = i ^ j;
                if (l > i) {
                    double va = s_v64[i], vb = s_v64[l];
                    int    ia = s_ki[i],  ib = s_ki[l];
                    bool beforeIL = (va > vb) || (va == vb && ia < ib);
                    bool up = ((i & k) == 0);
                    bool sw = up ? (!beforeIL) : beforeIL;
                    if (sw) {
                        s_v64[i] = vb; s_v64[l] = va;
                        s_ki[i]  = ib; s_ki[l]  = ia;
                    }
                }
            }
            __syncthreads();
        }
    }

    // ---------------- phase 4: f64 top-k cut + top-p + log-softmax ----------------
    if (tid == 0) {
        int kk = k50c;
        int Kkept;
        if (kk <= 50) Kkept = kk;
        else {
            double kth64 = s_v64[49];
            Kkept = 50;
            while (Kkept < kk && s_v64[Kkept] == kth64) ++Kkept;  // ties at rank 50 kept
        }
        double mx = s_v64[0];
        double D = 0.0;
        #pragma unroll 1
        for (int i = 0; i < Kkept; ++i) D += exp(s_v64[i] - mx);
        double c = 0.0;
        int Kp = 0;
        #pragma unroll 1
        for (int i = 0; i < Kkept; ++i) {
            bool keep = (i == 0) || (c <= 0.9);
            c += exp(s_v64[i] - mx) / D;
            if (keep) Kp = i + 1; else break;
        }
        double D2 = 0.0;
        #pragma unroll 1
        for (int i = 0; i < Kp; ++i) D2 += exp(s_v64[i] - mx);
        double lse = log(D2);
        s_rc = (float)((-1e9 - mx) - lse);
        #pragma unroll 1
        for (int i = 0; i < Kp; ++i) s_kof[i] = (float)((s_v64[i] - mx) - lse);
        s_kp = Kp;
    }
    __syncthreads();

    // ---------------- phase 5: disjoint masked fill + scatter ----------------
    for (int i = tid; i < BMW; i += NT) s_bm[i] = 0u;
    __syncthreads();
    if (tid < s_kp) {
        int tok = s_ki[tid];
        atomicOr(&s_bm[tok >> 5], 1u << (tok & 31));
    }
    __syncthreads();
    const int   kp = s_kp;
    const float rc = s_rc;
    auto kbit = [&](int t) -> uint32_t {
        return (s_bm[t >> 5] >> (t & 31)) & 1u;
    };
    {
        const int omis   = (int)(((size_t)orow >> 2) & 3);
        const int ohead  = (4 - omis) & 3;
        const int onq    = (VV - ohead) >> 2;
        const int ottail = ohead + (onq << 2);
        const float4 rc4 = make_float4(rc, rc, rc, rc);
        if (tid < ohead) { if (!kbit(tid)) orow[tid] = rc; }
        for (int q = tid; q < onq; q += NT) {
            int t = ohead + (q << 2);
            uint32_t any = kbit(t) | kbit(t + 1) | kbit(t + 2) | kbit(t + 3);
            if (!any) {
                *reinterpret_cast<float4*>(orow + t) = rc4;
            } else {
                if (!kbit(t + 0)) orow[t + 0] = rc;
                if (!kbit(t + 1)) orow[t + 1] = rc;
                if (!kbit(t + 2)) orow[t + 2] = rc;
                if (!kbit(t + 3)) orow[t + 3] = rc;
            }
        }
        if (ottail + tid < VV) { int t = ottail + tid; if (!kbit(t)) orow[t] = rc; }
    }
    if (tid < kp) orow[s_ki[tid]] = s_kof[tid];
}

extern "C" void kernel_launch(void* const* d_in, const int* in_sizes, int n_in,
                              void* d_out, int out_size, void* d_ws, size_t ws_size,
                              hipStream_t stream) {
    const float* logits = (const float*)d_in[0];
    const int*   prev   = (const int*)d_in[1];
    float*       out    = (float*)d_out;
    dim3 grid(BB * SS), block(NT);
    hipLaunchKernelGGL(sch_kernel, grid, block, 0, stream, logits, prev, out);
}

// Round 4
// 142.813 us; speedup vs baseline: 1.2111x; 1.2111x over previous
//
#include <hip/hip_runtime.h>
#include <cstdint>
#include <cfloat>
#include <math.h>

// Problem constants (match reference)
#define BB 16
#define SS 64
#define VV 50257
#define PP 64

#define NT 256          // threads per block
#define BINS 2048       // key histogram bins (top 11 bits of ordered key)
#define CAP 1536        // candidate buffer capacity
#define BMW 1572        // bitmap words: ceil(50257/32)=1571 (+1 pad for w1 read)
#define KCAP 128        // kept (top-k survivors) capacity
#define BCAP 512        // kth-bin member list capacity
#define TRAW 6.0f       // raw-domain candidate threshold (= 7.5 scaled * 0.8)

// monotone float->uint key (increasing)
__device__ __forceinline__ uint32_t fkey(float f) {
    uint32_t u = __float_as_uint(f);
    return u ^ ((uint32_t)((int32_t)u >> 31) | 0x80000000u);
}
__device__ __forceinline__ float key2f(uint32_t u) {
    uint32_t b = (u & 0x80000000u) ? (u ^ 0x80000000u) : ~u;
    return __uint_as_float(b);
}

__global__ __launch_bounds__(NT)
void sch_kernel(const float* __restrict__ logits,
                const int* __restrict__ prev,
                float* __restrict__ out)
{
    const int r   = blockIdx.x;            // row in [0, B*S)
    const int b   = r / SS;
    const int s   = r % SS;
    const int tid = threadIdx.x;
    const float* row  = logits + (size_t)r * VV;
    float*       orow = out    + (size_t)r * VV;

    __shared__ uint32_t s_bm[BMW];
    __shared__ float    s_cv[CAP];    // candidate value, PRE-TEMPERATURE domain
    __shared__ int      s_ci[CAP];
    __shared__ uint32_t s_hist[BINS];
    __shared__ uint32_t s_scan[NT];
    __shared__ int      s_ptok[PP];
    __shared__ float    s_ppen[PP];   // f32 pre-temp penalized value (selection only)
    __shared__ float    s_praw[PP];   // raw f32 logit of penalized token (this batch)
    __shared__ int      s_pneg[PP];   // all_neg flag
    __shared__ float    s_binv[BCAP];
    __shared__ double   s_v64[KCAP];  // f64 decision values of kept candidates
    __shared__ int      s_ki[KCAP];
    __shared__ float    s_kof[KCAP];  // final f32 log-probs (sorted order)
    __shared__ int   s_cnt, s_cntn, s_b50, s_need, s_cntb, s_k50, s_kp;
    __shared__ float s_kth, s_rc;

    // ---------------- phase 0: repetition-penalty setup ----------------
    for (int i = tid; i < BMW; i += NT) s_bm[i] = 0u;
    __syncthreads();
    if (tid < PP) {
        int tok = prev[s * PP + tid];
        bool allneg = true;
        float gown = 0.f;
        #pragma unroll 1
        for (int b2 = 0; b2 < BB; ++b2) {
            float g = logits[((size_t)b2 * SS + s) * (size_t)VV + tok];
            allneg = allneg && (g < 0.f);
            if (b2 == b) gown = g;
        }
        float pen = allneg ? (gown * 1.2f) : (gown / 1.2f);
        s_ptok[tid] = tok;
        s_ppen[tid] = pen;                 // pre-temp domain (selection only)
        s_praw[tid] = gown;
        s_pneg[tid] = allneg ? 1 : 0;
        atomicOr(&s_bm[tok >> 5], 1u << (tok & 31));
    }
    if (tid == 0) { s_cnt = 0; s_cntn = 0; }
    __syncthreads();

    // ---------------- streaming geometry ----------------
    const int mis   = (int)(((size_t)row >> 2) & 3);
    const int head  = (4 - mis) & 3;
    const int nq    = (VV - head) >> 2;
    const int ttail = head + (nq << 2);

    auto kbit = [&](int t) -> uint32_t {
        return (s_bm[t >> 5] >> (t & 31)) & 1u;
    };
    // fast path: raw-domain compare, skip penalized tokens (injected later)
    auto addRaw = [&](int t, float raw) {
        if (raw >= TRAW) {
            int pos = atomicAdd(&s_cnt, 1);
            atomicAdd(&s_cntn, 1);
            if (pos < CAP) { s_cv[pos] = raw; s_ci[pos] = t; }
        }
    };
    auto streamFast = [&]() {
        for (int t = tid; t < head; t += NT)
            { if (!kbit(t)) addRaw(t, row[t]); }
        for (int q = tid; q < nq; q += NT) {
            int t = head + (q << 2);
            float4 f = *reinterpret_cast<const float4*>(row + t);
            // one 64-bit bitmap window covers tokens t..t+3 even across words
            uint64_t ww = (uint64_t)s_bm[t >> 5] |
                          ((uint64_t)s_bm[(t >> 5) + 1] << 32);
            uint32_t nib = (uint32_t)(ww >> (t & 31)) & 0xFu;
            if (nib == 0u) {
                addRaw(t + 0, f.x);
                addRaw(t + 1, f.y);
                addRaw(t + 2, f.z);
                addRaw(t + 3, f.w);
            } else {
                if (!(nib & 1u)) addRaw(t + 0, f.x);
                if (!(nib & 2u)) addRaw(t + 1, f.y);
                if (!(nib & 4u)) addRaw(t + 2, f.z);
                if (!(nib & 8u)) addRaw(t + 3, f.w);
            }
        }
        for (int t = ttail + tid; t < VV; t += NT)
            { if (!kbit(t)) addRaw(t, row[t]); }
    };
    // full path (rare fallback): per-element penalty substitution, pre-temp domain
    auto procFull = [&](int t, float raw, bool doHist, float thr) {
        float v = raw;
        if (kbit(t)) {
            #pragma unroll 1
            for (int j = 0; j < PP; ++j)
                if (s_ptok[j] == t) { v = s_ppen[j]; break; }
        }
        if (!doHist) {
            if (v >= thr) {
                int pos = atomicAdd(&s_cnt, 1);
                if (pos < CAP) { s_cv[pos] = v; s_ci[pos] = t; }
            }
        } else {
            atomicAdd(&s_hist[fkey(v) >> 21], 1u);
        }
    };
    auto streamFull = [&](bool doHist, float thr) {
        for (int t = tid; t < head; t += NT) procFull(t, row[t], doHist, thr);
        for (int q = tid; q < nq; q += NT) {
            int t = head + (q << 2);
            float4 f = *reinterpret_cast<const float4*>(row + t);
            procFull(t + 0, f.x, doHist, thr);
            procFull(t + 1, f.y, doHist, thr);
            procFull(t + 2, f.z, doHist, thr);
            procFull(t + 3, f.w, doHist, thr);
        }
        for (int t = ttail + tid; t < VV; t += NT) procFull(t, row[t], doHist, thr);
    };
    auto findB50 = [&](int target) {
        __syncthreads();
        const int per = BINS / NT;
        int base = tid * per;
        uint32_t loc = 0;
        for (int k = 0; k < per; ++k) loc += s_hist[base + k];
        s_scan[tid] = loc;
        __syncthreads();
        for (int off = 1; off < NT; off <<= 1) {
            uint32_t add = (tid + off < NT) ? s_scan[tid + off] : 0u;
            __syncthreads();
            s_scan[tid] += add;
            __syncthreads();
        }
        uint32_t run = (tid + 1 < NT) ? s_scan[tid + 1] : 0u;
        for (int k = per - 1; k >= 0; --k) {
            uint32_t h = s_hist[base + k];
            uint32_t run2 = run + h;
            if (run < (uint32_t)target && run2 >= (uint32_t)target) {
                s_b50 = base + k;
                s_need = target - (int)run;
            }
            run = run2;
        }
        __syncthreads();
    };

    // ---------------- phase 1: collect candidates (1 global read) ----------------
    streamFast();
    __syncthreads();
    // inject penalized tokens (dedupe duplicates in prev list; first occurrence)
    if (tid < PP) {
        int tok = s_ptok[tid];
        bool first = true;
        for (int j = 0; j < tid; ++j)
            if (s_ptok[j] == tok) { first = false; break; }
        if (first) {
            int pos = atomicAdd(&s_cnt, 1);
            if (pos < CAP) { s_cv[pos] = s_ppen[tid]; s_ci[pos] = tok; }
        }
    }
    __syncthreads();
    int cnt = s_cnt;
    bool okc = (s_cntn >= 50 && cnt <= CAP);
    if (!okc) {
        // robust fallback: full-row histogram -> exact usable threshold -> recollect
        for (int i = tid; i < BINS; i += NT) s_hist[i] = 0u;
        __syncthreads();
        streamFull(true, 0.f);
        findB50(50);
        float thrF = key2f((uint32_t)s_b50 << 21);
        if (tid == 0) s_cnt = 0;
        __syncthreads();
        streamFull(false, thrF);
        __syncthreads();
        cnt = s_cnt;
    }
    const int cntc = min(cnt, CAP);

    // ---------------- phase 2: f32 kth (50th largest) among candidates ----------------
    for (int i = tid; i < BINS; i += NT) s_hist[i] = 0u;
    if (tid == 0) { s_cntb = 0; s_kth = -FLT_MAX; }
    __syncthreads();
    for (int i = tid; i < cntc; i += NT)
        atomicAdd(&s_hist[fkey(s_cv[i]) >> 21], 1u);
    findB50(50);
    const int b50 = s_b50, need = s_need;
    for (int i = tid; i < cntc; i += NT) {
        if ((int)(fkey(s_cv[i]) >> 21) == b50) {
            int p = atomicAdd(&s_cntb, 1);
            if (p < BCAP) s_binv[p] = s_cv[i];
        }
    }
    __syncthreads();
    const int cb = min(s_cntb, BCAP);
    for (int i = tid; i < cb; i += NT) {   // rank-count (grid-stride; cb can exceed NT)
        float vi = s_binv[i];
        int gt = 0, ge = 0;
        for (int j = 0; j < cb; ++j) {
            float vj = s_binv[j];
            gt += (vj > vi);
            ge += (vj >= vi);
        }
        if (gt < need && ge >= need) s_kth = vi;   // benign race: identical value
    }
    if (tid == 0) s_k50 = 0;
    __syncthreads();
    const float kth = s_kth;

    // ---------------- phase 3: gather kept (margin below kth32), f64 values ----------
    // {v32 >= kth32 - margin} contains the f64-top-50 (monotone rounding + ulp guard)
    const float gthr = kth - 1e-4f;
    for (int i = tid; i < cntc; i += NT) {
        if (s_cv[i] >= gthr) {
            int p = atomicAdd(&s_k50, 1);
            if (p < KCAP) {
                int tok = s_ci[i];
                double v64;
                if (kbit(tok)) {                   // penalized: exact f64 recompute
                    int pj = 0;
                    #pragma unroll 1
                    for (int j = 0; j < PP; ++j)
                        if (s_ptok[j] == tok) { pj = j; break; }
                    double g = (double)s_praw[pj];
                    double pen = s_pneg[pj] ? (g * 1.2) : (g / 1.2);
                    v64 = pen / 0.8;
                } else {
                    v64 = (double)s_cv[i] / 0.8;   // raw rode along in s_cv
                }
                s_v64[p] = v64;
                s_ki[p]  = tok;
            }
        }
    }
    __syncthreads();
    const int k50c = min(s_k50, KCAP);
    for (int i = k50c + tid; i < KCAP; i += NT) {
        s_v64[i] = -1e300;
        s_ki[i]  = (1 << 30) + i;
    }
    __syncthreads();

    // bitonic sort, 128 slots: descending v64, tie -> ascending token idx
    for (int k = 2; k <= KCAP; k <<= 1) {
        for (int j = k >> 1; j > 0; j >>= 1) {
            if (tid < KCAP) {
                int i = tid, l = i ^ j;
                if (l > i) {
                    double va = s_v64[i], vb = s_v64[l];
                    int    ia = s_ki[i],  ib = s_ki[l];
                    bool beforeIL = (va > vb) || (va == vb && ia < ib);
                    bool up = ((i & k) == 0);
                    bool sw = up ? (!beforeIL) : beforeIL;
                    if (sw) {
                        s_v64[i] = vb; s_v64[l] = va;
                        s_ki[i]  = ib; s_ki[l]  = ia;
                    }
                }
            }
            __syncthreads();
        }
    }

    // ---------------- phase 4: f64 top-k cut + top-p + log-softmax ----------------
    if (tid == 0) {
        int kk = k50c;
        int Kkept;
        if (kk <= 50) Kkept = kk;
        else {
            double kth64 = s_v64[49];
            Kkept = 50;
            while (Kkept < kk && s_v64[Kkept] == kth64) ++Kkept;
        }
        double mx = s_v64[0];
        double D = 0.0;
        #pragma unroll 1
        for (int i = 0; i < Kkept; ++i) D += exp(s_v64[i] - mx);
        double c = 0.0;
        int Kp = 0;
        #pragma unroll 1
        for (int i = 0; i < Kkept; ++i) {
            bool keep = (i == 0) || (c <= 0.9);
            c += exp(s_v64[i] - mx) / D;
            if (keep) Kp = i + 1; else break;
        }
        double D2 = 0.0;
        #pragma unroll 1
        for (int i = 0; i < Kp; ++i) D2 += exp(s_v64[i] - mx);
        double lse = log(D2);
        s_rc = (float)((-1e9 - mx) - lse);
        #pragma unroll 1
        for (int i = 0; i < Kp; ++i) s_kof[i] = (float)((s_v64[i] - mx) - lse);
        s_kp = Kp;
    }
    __syncthreads();

    // ---------------- phase 5: disjoint masked fill + scatter ----------------
    // rebuild bitmap for FINAL kept tokens; word-nibble fast path for the fill
    for (int i = tid; i < BMW; i += NT) s_bm[i] = 0u;
    __syncthreads();
    if (tid < s_kp) {
        int tok = s_ki[tid];
        atomicOr(&s_bm[tok >> 5], 1u << (tok & 31));
    }
    __syncthreads();
    const int   kp = s_kp;
    const float rc = s_rc;
    {
        const int omis   = (int)(((size_t)orow >> 2) & 3);
        const int ohead  = (4 - omis) & 3;
        const int onq    = (VV - ohead) >> 2;
        const int ottail = ohead + (onq << 2);
        const float4 rc4 = make_float4(rc, rc, rc, rc);
        for (int t = tid; t < ohead; t += NT) { if (!kbit(t)) orow[t] = rc; }
        for (int q = tid; q < onq; q += NT) {
            int t = ohead + (q << 2);
            uint64_t ww = (uint64_t)s_bm[t >> 5] |
                          ((uint64_t)s_bm[(t >> 5) + 1] << 32);
            uint32_t nib = (uint32_t)(ww >> (t & 31)) & 0xFu;
            if (nib == 0u) {
                *reinterpret_cast<float4*>(orow + t) = rc4;
            } else {
                if (!(nib & 1u)) orow[t + 0] = rc;
                if (!(nib & 2u)) orow[t + 1] = rc;
                if (!(nib & 4u)) orow[t + 2] = rc;
                if (!(nib & 8u)) orow[t + 3] = rc;
            }
        }
        for (int t = ottail + tid; t < VV; t += NT) { if (!kbit(t)) orow[t] = rc; }
    }
    if (tid < kp) orow[s_ki[tid]] = s_kof[tid];
}

extern "C" void kernel_launch(void* const* d_in, const int* in_sizes, int n_in,
                              void* d_out, int out_size, void* d_ws, size_t ws_size,
                              hipStream_t stream) {
    const float* logits = (const float*)d_in[0];
    const int*   prev   = (const int*)d_in[1];
    float*       out    = (float*)d_out;
    dim3 grid(BB * SS), block(NT);
    hipLaunchKernelGGL(sch_kernel, grid, block, 0, stream, logits, prev, out);
}

// Round 5
// 115.553 us; speedup vs baseline: 1.4968x; 1.2359x over previous
//
#include <hip/hip_runtime.h>
#include <cstdint>
#include <cfloat>
#include <math.h>

// Problem constants (match reference)
#define BB 16
#define SS 64
#define VV 50257
#define PP 64

#define NT 512          // threads per block (8 waves; 4 blocks/CU -> 32 waves/CU)
#define BINS 2048       // key histogram bins (top 11 bits of ordered key)
#define CAP 1536        // candidate buffer capacity
#define BMW 1572        // bitmap words: ceil(50257/32)=1571 (+1 pad)
#define KCAP 128        // kept (top-k survivors) capacity
#define BCAP 512        // kth-bin member list capacity
#define TRAW 6.0f       // raw-domain candidate threshold (= 7.5 scaled * 0.8)

// monotone float->uint key (increasing)
__device__ __forceinline__ uint32_t fkey(float f) {
    uint32_t u = __float_as_uint(f);
    return u ^ ((uint32_t)((int32_t)u >> 31) | 0x80000000u);
}
__device__ __forceinline__ float key2f(uint32_t u) {
    uint32_t b = (u & 0x80000000u) ? (u ^ 0x80000000u) : ~u;
    return __uint_as_float(b);
}

__global__ __launch_bounds__(NT)
void sch_kernel(const float* __restrict__ logits,
                const int* __restrict__ prev,
                float* __restrict__ out)
{
    const int r   = blockIdx.x;            // row in [0, B*S)
    const int b   = r / SS;
    const int s   = r % SS;
    const int tid = threadIdx.x;
    const float* row  = logits + (size_t)r * VV;
    float*       orow = out    + (size_t)r * VV;

    __shared__ uint32_t s_bm[BMW];
    __shared__ float    s_cv[CAP];    // candidate value, PRE-TEMPERATURE domain
    __shared__ int      s_ci[CAP];
    __shared__ uint32_t s_hist[BINS];
    __shared__ uint32_t s_scan[NT];
    __shared__ int      s_ptok[PP];
    __shared__ float    s_ppen[PP];   // f32 pre-temp penalized value (selection only)
    __shared__ float    s_praw[PP];   // raw f32 logit of penalized token (this batch)
    __shared__ int      s_pneg[PP];   // all_neg flag
    __shared__ float    s_binv[BCAP];
    __shared__ double   s_v64[KCAP];  // f64 decision values of kept candidates
    __shared__ int      s_ki[KCAP];
    __shared__ float    s_kof[KCAP];  // final f32 log-probs (sorted order)
    __shared__ int   s_cnt, s_cntinv, s_b50, s_need, s_cntb, s_k50, s_kp;
    __shared__ float s_kth, s_rc;

    // ---------------- phase 0: repetition-penalty setup ----------------
    for (int i = tid; i < BMW; i += NT) s_bm[i] = 0u;
    __syncthreads();
    if (tid < PP) {
        int tok = prev[s * PP + tid];
        bool allneg = true;
        float gown = 0.f;
        #pragma unroll 1
        for (int b2 = 0; b2 < BB; ++b2) {
            float g = logits[((size_t)b2 * SS + s) * (size_t)VV + tok];
            allneg = allneg && (g < 0.f);
            if (b2 == b) gown = g;
        }
        float pen = allneg ? (gown * 1.2f) : (gown / 1.2f);
        s_ptok[tid] = tok;
        s_ppen[tid] = pen;                 // pre-temp domain (selection only)
        s_praw[tid] = gown;
        s_pneg[tid] = allneg ? 1 : 0;
        atomicOr(&s_bm[tok >> 5], 1u << (tok & 31));
    }
    if (tid == 0) { s_cnt = 0; s_cntinv = 0; }
    __syncthreads();

    // ---------------- streaming geometry ----------------
    const int mis   = (int)(((size_t)row >> 2) & 3);
    const int head  = (4 - mis) & 3;
    const int nq    = (VV - head) >> 2;
    const int ttail = head + (nq << 2);
    const float4* p4 = reinterpret_cast<const float4*>(row + head);

    auto kbit = [&](int t) -> uint32_t {
        return (s_bm[t >> 5] >> (t & 31)) & 1u;
    };
    auto addRaw = [&](int t, float raw) {
        if (raw >= TRAW) {
            int pos = atomicAdd(&s_cnt, 1);
            if (pos < CAP) { s_cv[pos] = raw; s_ci[pos] = t; }
        }
    };
    // hot read stream: NO LDS, 4-deep unrolled for MLP
    auto streamFast = [&]() {
        for (int t = tid; t < head; t += NT) addRaw(t, row[t]);
        int base = 0;
        for (; base + 4 * NT <= nq; base += 4 * NT) {
            float4 f[4];
            #pragma unroll
            for (int u = 0; u < 4; ++u) f[u] = p4[base + tid + u * NT];
            #pragma unroll
            for (int u = 0; u < 4; ++u) {
                int t = head + ((base + tid + u * NT) << 2);
                addRaw(t + 0, f[u].x);
                addRaw(t + 1, f[u].y);
                addRaw(t + 2, f[u].z);
                addRaw(t + 3, f[u].w);
            }
        }
        for (int q = base + tid; q < nq; q += NT) {
            float4 f = p4[q];
            int t = head + (q << 2);
            addRaw(t + 0, f.x);
            addRaw(t + 1, f.y);
            addRaw(t + 2, f.z);
            addRaw(t + 3, f.w);
        }
        for (int t = ttail + tid; t < VV; t += NT) addRaw(t, row[t]);
    };
    // full path (rare fallback): per-element penalty substitution, pre-temp domain
    auto procFull = [&](int t, float raw, bool doHist, float thr) {
        float v = raw;
        if (kbit(t)) {
            #pragma unroll 1
            for (int j = 0; j < PP; ++j)
                if (s_ptok[j] == t) { v = s_ppen[j]; break; }
        }
        if (!doHist) {
            if (v >= thr) {
                int pos = atomicAdd(&s_cnt, 1);
                if (pos < CAP) { s_cv[pos] = v; s_ci[pos] = t; }
            }
        } else {
            atomicAdd(&s_hist[fkey(v) >> 21], 1u);
        }
    };
    auto streamFull = [&](bool doHist, float thr) {
        for (int t = tid; t < head; t += NT) procFull(t, row[t], doHist, thr);
        for (int q = tid; q < nq; q += NT) {
            float4 f = p4[q];
            int t = head + (q << 2);
            procFull(t + 0, f.x, doHist, thr);
            procFull(t + 1, f.y, doHist, thr);
            procFull(t + 2, f.z, doHist, thr);
            procFull(t + 3, f.w, doHist, thr);
        }
        for (int t = ttail + tid; t < VV; t += NT) procFull(t, row[t], doHist, thr);
    };
    auto findB50 = [&](int target) {
        __syncthreads();
        const int per = BINS / NT;
        int base = tid * per;
        uint32_t loc = 0;
        for (int k = 0; k < per; ++k) loc += s_hist[base + k];
        s_scan[tid] = loc;
        __syncthreads();
        for (int off = 1; off < NT; off <<= 1) {
            uint32_t add = (tid + off < NT) ? s_scan[tid + off] : 0u;
            __syncthreads();
            s_scan[tid] += add;
            __syncthreads();
        }
        uint32_t run = (tid + 1 < NT) ? s_scan[tid + 1] : 0u;
        for (int k = per - 1; k >= 0; --k) {
            uint32_t h = s_hist[base + k];
            uint32_t run2 = run + h;
            if (run < (uint32_t)target && run2 >= (uint32_t)target) {
                s_b50 = base + k;
                s_need = target - (int)run;
            }
            run = run2;
        }
        __syncthreads();
    };
    // exact full-row fallback: histogram -> usable threshold -> recollect (with
    // penalty substitution). Produces a candidate set needing NO fixup/inject.
    auto doFallback = [&]() {
        for (int i = tid; i < BINS; i += NT) s_hist[i] = 0u;
        __syncthreads();
        streamFull(true, 0.f);
        findB50(50);
        float thrF = key2f((uint32_t)s_b50 << 21);
        if (tid == 0) s_cnt = 0;
        __syncthreads();
        streamFull(false, thrF);
        __syncthreads();
    };
    // f32 kth (50th largest) among candidates -> s_kth
    auto computeKth = [&]() {
        for (int i = tid; i < BINS; i += NT) s_hist[i] = 0u;
        if (tid == 0) { s_cntb = 0; s_kth = -FLT_MAX; }
        __syncthreads();
        int cc = min(s_cnt, CAP);
        for (int i = tid; i < cc; i += NT)
            atomicAdd(&s_hist[fkey(s_cv[i]) >> 21], 1u);
        findB50(50);
        int b50 = s_b50, need = s_need;
        for (int i = tid; i < cc; i += NT) {
            if ((int)(fkey(s_cv[i]) >> 21) == b50) {
                int p = atomicAdd(&s_cntb, 1);
                if (p < BCAP) s_binv[p] = s_cv[i];
            }
        }
        __syncthreads();
        int cb = min(s_cntb, BCAP);
        for (int i = tid; i < cb; i += NT) {    // rank-count (grid-stride)
            float vi = s_binv[i];
            int gt = 0, ge = 0;
            for (int j = 0; j < cb; ++j) {
                float vj = s_binv[j];
                gt += (vj > vi);
                ge += (vj >= vi);
            }
            if (gt < need && ge >= need) s_kth = vi;   // benign race: same value
        }
        __syncthreads();
    };

    // ---------------- phase 1: collect candidates (1 global read) ----------------
    streamFast();
    __syncthreads();
    const int cntRaw = min(s_cnt, CAP);
    // fixup: invalidate raw entries of penalized tokens (values differ)
    for (int i = tid; i < cntRaw; i += NT) {
        if (kbit(s_ci[i])) {
            s_cv[i] = -FLT_MAX;
            atomicAdd(&s_cntinv, 1);
        }
    }
    __syncthreads();
    // inject penalized tokens with pen values (dedupe by first occurrence)
    if (tid < PP) {
        int tok = s_ptok[tid];
        bool first = true;
        for (int j = 0; j < tid; ++j)
            if (s_ptok[j] == tok) { first = false; break; }
        if (first) {
            int pos = atomicAdd(&s_cnt, 1);
            if (pos < CAP) { s_cv[pos] = s_ppen[tid]; s_ci[pos] = tok; }
        }
    }
    __syncthreads();
    bool fellback = false;
    {
        bool okc = (s_cnt <= CAP) && ((cntRaw - s_cntinv) >= 50);
        if (!okc) { doFallback(); fellback = true; }
    }

    // ---------------- phase 2: f32 kth among candidates ----------------
    computeKth();
    if (!fellback && (s_kth - 1e-4f < TRAW)) {   // margin guard: superset unproven
        doFallback();
        computeKth();
    }
    if (tid == 0) s_k50 = 0;
    __syncthreads();
    const float kth = s_kth;

    // ---------------- phase 3: gather kept (margin below kth32), f64 values ----------
    const float gthr = kth - 1e-4f;
    const int cntc = min(s_cnt, CAP);
    for (int i = tid; i < cntc; i += NT) {
        if (s_cv[i] >= gthr) {
            int p = atomicAdd(&s_k50, 1);
            if (p < KCAP) {
                int tok = s_ci[i];
                double v64;
                if (kbit(tok)) {                   // penalized: exact f64 recompute
                    int pj = 0;
                    #pragma unroll 1
                    for (int j = 0; j < PP; ++j)
                        if (s_ptok[j] == tok) { pj = j; break; }
                    double g = (double)s_praw[pj];
                    double pen = s_pneg[pj] ? (g * 1.2) : (g / 1.2);
                    v64 = pen / 0.8;
                } else {
                    v64 = (double)s_cv[i] / 0.8;   // raw rode along in s_cv
                }
                s_v64[p] = v64;
                s_ki[p]  = tok;
            }
        }
    }
    __syncthreads();
    const int k50c = min(s_k50, KCAP);
    for (int i = k50c + tid; i < KCAP; i += NT) {
        s_v64[i] = -1e300;
        s_ki[i]  = (1 << 30) + i;
    }
    __syncthreads();

    // bitonic sort, 128 slots: descending v64, tie -> ascending token idx
    for (int k = 2; k <= KCAP; k <<= 1) {
        for (int j = k >> 1; j > 0; j >>= 1) {
            if (tid < KCAP) {
                int i = tid, l = i ^ j;
                if (l > i) {
                    double va = s_v64[i], vb = s_v64[l];
                    int    ia = s_ki[i],  ib = s_ki[l];
                    bool beforeIL = (va > vb) || (va == vb && ia < ib);
                    bool up = ((i & k) == 0);
                    bool sw = up ? (!beforeIL) : beforeIL;
                    if (sw) {
                        s_v64[i] = vb; s_v64[l] = va;
                        s_ki[i]  = ib; s_ki[l]  = ia;
                    }
                }
            }
            __syncthreads();
        }
    }

    // ---------------- phase 4: f64 top-k cut + top-p + log-softmax ----------------
    if (tid == 0) {
        int kk = k50c;
        int Kkept;
        if (kk <= 50) Kkept = kk;
        else {
            double kth64 = s_v64[49];
            Kkept = 50;
            while (Kkept < kk && s_v64[Kkept] == kth64) ++Kkept;
        }
        double mx = s_v64[0];
        double D = 0.0;
        #pragma unroll 1
        for (int i = 0; i < Kkept; ++i) D += exp(s_v64[i] - mx);
        double c = 0.0;
        int Kp = 0;
        #pragma unroll 1
        for (int i = 0; i < Kkept; ++i) {
            bool keep = (i == 0) || (c <= 0.9);
            c += exp(s_v64[i] - mx) / D;
            if (keep) Kp = i + 1; else break;
        }
        double D2 = 0.0;
        #pragma unroll 1
        for (int i = 0; i < Kp; ++i) D2 += exp(s_v64[i] - mx);
        double lse = log(D2);
        s_rc = (float)((-1e9 - mx) - lse);
        #pragma unroll 1
        for (int i = 0; i < Kp; ++i) s_kof[i] = (float)((s_v64[i] - mx) - lse);
        s_kp = Kp;
    }
    __syncthreads();

    // ---------------- phase 5: unconditional fill, drain, scatter ----------------
    // __syncthreads() forces s_waitcnt vmcnt(0) before s_barrier, so every fill
    // store is complete before any scatter store issues -> scatter wins.
    const float rc = s_rc;
    {
        const int omis   = (int)(((size_t)orow >> 2) & 3);
        const int ohead  = (4 - omis) & 3;
        const int onq    = (VV - ohead) >> 2;
        const int ottail = ohead + (onq << 2);
        float4* o4 = reinterpret_cast<float4*>(orow + ohead);
        const float4 rc4 = make_float4(rc, rc, rc, rc);
        for (int t = tid; t < ohead; t += NT) orow[t] = rc;
        for (int q = tid; q < onq; q += NT) o4[q] = rc4;
        for (int t = ottail + tid; t < VV; t += NT) orow[t] = rc;
    }
    __syncthreads();
    if (tid < s_kp) orow[s_ki[tid]] = s_kof[tid];
}

extern "C" void kernel_launch(void* const* d_in, const int* in_sizes, int n_in,
                              void* d_out, int out_size, void* d_ws, size_t ws_size,
                              hipStream_t stream) {
    const float* logits = (const float*)d_in[0];
    const int*   prev   = (const int*)d_in[1];
    float*       out    = (float*)d_out;
    dim3 grid(BB * SS), block(NT);
    hipLaunchKernelGGL(sch_kernel, grid, block, 0, stream, logits, prev, out);
}

// Round 6
// 113.039 us; speedup vs baseline: 1.5301x; 1.0222x over previous
//
#include <hip/hip_runtime.h>
#include <cstdint>
#include <cfloat>
#include <math.h>

// Problem constants (match reference)
#define BB 16
#define SS 64
#define VV 50257
#define PP 64

#define NT 512          // threads per block (8 waves; 4 blocks/CU -> 32 waves/CU)
#define BINS 2048       // key histogram bins (top 11 bits of ordered key)
#define CAP 1536        // candidate buffer capacity
#define BMW 1572        // bitmap words: ceil(50257/32)=1571 (+1 pad)
#define KCAP 128        // kept (top-k survivors) capacity
#define BCAP 512        // kth-bin member list capacity
#define TRAW 6.0f       // raw-domain candidate threshold (= 7.5 scaled * 0.8)

// monotone float->uint key (increasing)
__device__ __forceinline__ uint32_t fkey(float f) {
    uint32_t u = __float_as_uint(f);
    return u ^ ((uint32_t)((int32_t)u >> 31) | 0x80000000u);
}
__device__ __forceinline__ float key2f(uint32_t u) {
    uint32_t b = (u & 0x80000000u) ? (u ^ 0x80000000u) : ~u;
    return __uint_as_float(b);
}

__global__ __launch_bounds__(NT)
void sch_kernel(const float* __restrict__ logits,
                const int* __restrict__ prev,
                float* __restrict__ out)
{
    const int r   = blockIdx.x;            // row in [0, B*S)
    const int b   = r / SS;
    const int s   = r % SS;
    const int tid = threadIdx.x;
    const float* row  = logits + (size_t)r * VV;
    float*       orow = out    + (size_t)r * VV;

    __shared__ uint32_t s_bm[BMW];
    __shared__ float    s_cv[CAP];    // candidate value, PRE-TEMPERATURE domain
    __shared__ int      s_ci[CAP];
    __shared__ uint32_t s_hist[BINS];
    __shared__ uint32_t s_scan[16];   // 8 wave totals + 8 wave prefixes
    __shared__ int      s_ptok[PP];
    __shared__ float    s_ppen[PP];   // f32 pre-temp penalized value (selection only)
    __shared__ float    s_praw[PP];   // raw f32 logit of penalized token (this batch)
    __shared__ int      s_pneg[PP];   // all_neg flag
    __shared__ float    s_binv[BCAP];
    __shared__ double   s_v64[KCAP];  // f64 decision values of kept candidates
    __shared__ double   s_e64[KCAP];  // f64 exp(v-mx), parallel-computed
    __shared__ int      s_ki[KCAP];
    __shared__ float    s_kof[KCAP];  // final f32 log-probs (sorted order)
    __shared__ int    s_cnt, s_cntinv, s_b50, s_need, s_cntb, s_k50, s_kp, s_Kk;
    __shared__ float  s_kth, s_rc;
    __shared__ double s_lse;

    // ---------------- phase 0: repetition-penalty setup (parallel gather) ----------
    for (int i = tid; i < BMW; i += NT) s_bm[i] = 0u;
    if (tid < PP) s_pneg[tid] = 1;
    if (tid == 0) { s_cnt = 0; s_cntinv = 0; }
    __syncthreads();
    // 64 tokens x 16 batches = 1024 independent scattered loads over 512 threads
    for (int pair = tid; pair < PP * BB; pair += NT) {
        int ti = pair & (PP - 1);
        int b2 = pair >> 6;
        int tok = prev[s * PP + ti];
        float g = logits[((size_t)b2 * SS + s) * (size_t)VV + tok];
        if (g >= 0.f) atomicAnd(&s_pneg[ti], 0);
        if (b2 == b) { s_praw[ti] = g; s_ptok[ti] = tok; }
    }
    __syncthreads();
    if (tid < PP) {
        float gown = s_praw[tid];
        float pen = s_pneg[tid] ? (gown * 1.2f) : (gown / 1.2f);
        s_ppen[tid] = pen;                 // pre-temp domain (selection only)
        int tok = s_ptok[tid];
        atomicOr(&s_bm[tok >> 5], 1u << (tok & 31));
    }
    __syncthreads();

    // ---------------- streaming geometry ----------------
    const int mis   = (int)(((size_t)row >> 2) & 3);
    const int head  = (4 - mis) & 3;
    const int nq    = (VV - head) >> 2;
    const int ttail = head + (nq << 2);
    const float4* p4 = reinterpret_cast<const float4*>(row + head);

    auto kbit = [&](int t) -> uint32_t {
        return (s_bm[t >> 5] >> (t & 31)) & 1u;
    };
    auto addRaw = [&](int t, float raw) {
        if (raw >= TRAW) {
            int pos = atomicAdd(&s_cnt, 1);
            if (pos < CAP) { s_cv[pos] = raw; s_ci[pos] = t; }
        }
    };
    // hot read stream: NO LDS on the fast path, 4-deep unrolled for MLP
    auto streamFast = [&]() {
        for (int t = tid; t < head; t += NT) addRaw(t, row[t]);
        int base = 0;
        for (; base + 4 * NT <= nq; base += 4 * NT) {
            float4 f[4];
            #pragma unroll
            for (int u = 0; u < 4; ++u) f[u] = p4[base + tid + u * NT];
            #pragma unroll
            for (int u = 0; u < 4; ++u) {
                int t = head + ((base + tid + u * NT) << 2);
                addRaw(t + 0, f[u].x);
                addRaw(t + 1, f[u].y);
                addRaw(t + 2, f[u].z);
                addRaw(t + 3, f[u].w);
            }
        }
        for (int q = base + tid; q < nq; q += NT) {
            float4 f = p4[q];
            int t = head + (q << 2);
            addRaw(t + 0, f.x);
            addRaw(t + 1, f.y);
            addRaw(t + 2, f.z);
            addRaw(t + 3, f.w);
        }
        for (int t = ttail + tid; t < VV; t += NT) addRaw(t, row[t]);
    };
    // full path (rare fallback): per-element penalty substitution, pre-temp domain
    auto procFull = [&](int t, float raw, bool doHist, float thr) {
        float v = raw;
        if (kbit(t)) {
            #pragma unroll 1
            for (int j = 0; j < PP; ++j)
                if (s_ptok[j] == t) { v = s_ppen[j]; break; }
        }
        if (!doHist) {
            if (v >= thr) {
                int pos = atomicAdd(&s_cnt, 1);
                if (pos < CAP) { s_cv[pos] = v; s_ci[pos] = t; }
            }
        } else {
            atomicAdd(&s_hist[fkey(v) >> 21], 1u);
        }
    };
    auto streamFull = [&](bool doHist, float thr) {
        for (int t = tid; t < head; t += NT) procFull(t, row[t], doHist, thr);
        for (int q = tid; q < nq; q += NT) {
            float4 f = p4[q];
            int t = head + (q << 2);
            procFull(t + 0, f.x, doHist, thr);
            procFull(t + 1, f.y, doHist, thr);
            procFull(t + 2, f.z, doHist, thr);
            procFull(t + 3, f.w, doHist, thr);
        }
        for (int t = ttail + tid; t < VV; t += NT) procFull(t, row[t], doHist, thr);
    };
    // suffix "find bin crossing target from top", shfl-scan version (2 barriers)
    auto findB50 = [&](int target) {
        __syncthreads();                     // histogram complete
        const int per = BINS / NT;           // 4 bins per thread
        int base = tid * per;
        uint32_t loc = 0;
        #pragma unroll
        for (int k2 = 0; k2 < per; ++k2) loc += s_hist[base + k2];
        uint32_t incl = loc;                 // wave-level inclusive scan
        #pragma unroll
        for (int off = 1; off < 64; off <<= 1) {
            uint32_t u = (uint32_t)__shfl_up((int)incl, off, 64);
            if ((tid & 63) >= off) incl += u;
        }
        int wid = tid >> 6;
        if ((tid & 63) == 63) s_scan[wid] = incl;
        __syncthreads();
        if (tid < 8) {                       // tiny exclusive wave-prefix
            uint32_t p = 0;
            for (int w = 0; w < tid; ++w) p += s_scan[w];
            s_scan[8 + tid] = p;
        }
        __syncthreads();
        uint32_t pre_incl = s_scan[8 + wid] + incl;
        uint32_t total    = s_scan[8 + 7] + s_scan[7];
        uint32_t run = total - pre_incl;     // sum of bins above my top bin
        for (int k2 = per - 1; k2 >= 0; --k2) {
            uint32_t h = s_hist[base + k2];
            uint32_t run2 = run + h;
            if (run < (uint32_t)target && run2 >= (uint32_t)target) {
                s_b50 = base + k2;
                s_need = target - (int)run;
            }
            run = run2;
        }
        __syncthreads();
    };
    auto doFallback = [&]() {
        for (int i = tid; i < BINS; i += NT) s_hist[i] = 0u;
        __syncthreads();
        streamFull(true, 0.f);
        findB50(50);
        float thrF = key2f((uint32_t)s_b50 << 21);
        if (tid == 0) s_cnt = 0;
        __syncthreads();
        streamFull(false, thrF);
        __syncthreads();
    };
    auto computeKth = [&]() {
        for (int i = tid; i < BINS; i += NT) s_hist[i] = 0u;
        if (tid == 0) { s_cntb = 0; s_kth = -FLT_MAX; }
        __syncthreads();
        int cc = min(s_cnt, CAP);
        for (int i = tid; i < cc; i += NT)
            atomicAdd(&s_hist[fkey(s_cv[i]) >> 21], 1u);
        findB50(50);
        int b50 = s_b50, need = s_need;
        for (int i = tid; i < cc; i += NT) {
            if ((int)(fkey(s_cv[i]) >> 21) == b50) {
                int p = atomicAdd(&s_cntb, 1);
                if (p < BCAP) s_binv[p] = s_cv[i];
            }
        }
        __syncthreads();
        int cb = min(s_cntb, BCAP);
        for (int i = tid; i < cb; i += NT) {    // rank-count (grid-stride)
            float vi = s_binv[i];
            int gt = 0, ge = 0;
            for (int j = 0; j < cb; ++j) {
                float vj = s_binv[j];
                gt += (vj > vi);
                ge += (vj >= vi);
            }
            if (gt < need && ge >= need) s_kth = vi;   // benign race: same value
        }
        __syncthreads();
    };

    // ---------------- phase 1: collect candidates (1 global read) ----------------
    streamFast();
    __syncthreads();
    const int cntRaw = min(s_cnt, CAP);
    for (int i = tid; i < cntRaw; i += NT) {     // invalidate penalized raw entries
        if (kbit(s_ci[i])) {
            s_cv[i] = -FLT_MAX;
            atomicAdd(&s_cntinv, 1);
        }
    }
    __syncthreads();
    if (tid < PP) {                              // inject pen values (dedupe)
        int tok = s_ptok[tid];
        bool first = true;
        for (int j = 0; j < tid; ++j)
            if (s_ptok[j] == tok) { first = false; break; }
        if (first) {
            int pos = atomicAdd(&s_cnt, 1);
            if (pos < CAP) { s_cv[pos] = s_ppen[tid]; s_ci[pos] = tok; }
        }
    }
    __syncthreads();
    bool fellback = false;
    {
        bool okc = (s_cnt <= CAP) && ((cntRaw - s_cntinv) >= 50);
        if (!okc) { doFallback(); fellback = true; }
    }

    // ---------------- phase 2: f32 kth among candidates ----------------
    computeKth();
    if (!fellback && (s_kth - 1e-4f < TRAW)) {   // margin guard: superset unproven
        doFallback();
        computeKth();
    }
    if (tid == 0) s_k50 = 0;
    __syncthreads();
    const float kth = s_kth;

    // ---------------- phase 3: gather kept (margin below kth32), f64 values ----------
    const float gthr = kth - 1e-4f;
    const int cntc = min(s_cnt, CAP);
    for (int i = tid; i < cntc; i += NT) {
        if (s_cv[i] >= gthr) {
            int p = atomicAdd(&s_k50, 1);
            if (p < KCAP) {
                int tok = s_ci[i];
                double v64;
                if (kbit(tok)) {                   // penalized: exact f64 recompute
                    int pj = 0;
                    #pragma unroll 1
                    for (int j = 0; j < PP; ++j)
                        if (s_ptok[j] == tok) { pj = j; break; }
                    double g = (double)s_praw[pj];
                    double pen = s_pneg[pj] ? (g * 1.2) : (g / 1.2);
                    v64 = pen / 0.8;
                } else {
                    v64 = (double)s_cv[i] / 0.8;   // raw rode along in s_cv
                }
                s_v64[p] = v64;
                s_ki[p]  = tok;
            }
        }
    }
    __syncthreads();
    const int k50c = min(s_k50, KCAP);
    for (int i = k50c + tid; i < KCAP; i += NT) {
        s_v64[i] = -1e300;
        s_ki[i]  = (1 << 30) + i;
    }
    __syncthreads();

    // ---------------- single-wave register bitonic sort (128 slots, 0 barriers) ----
    // lane l holds slots l and l+64; descending v64, tie -> ascending token idx.
    // Same comparator as the LDS bitonic -> identical final permutation.
    if (tid < 64) {
        int l = tid;
        double v0 = s_v64[l],    v1 = s_v64[l + 64];
        int    i0 = s_ki[l],     i1 = s_ki[l + 64];
        for (int k = 2; k <= KCAP; k <<= 1) {
            for (int j = k >> 1; j > 0; j >>= 1) {
                if (j >= 64) {          // j==64 (k==128): in-lane slot pair, up=true
                    bool before = (v0 > v1) || (v0 == v1 && i0 < i1);
                    if (!before) {
                        double tv = v0; v0 = v1; v1 = tv;
                        int    ti = i0; i0 = i1; i1 = ti;
                    }
                } else {
                    double nv0 = __shfl_xor(v0, j, 64);
                    double nv1 = __shfl_xor(v1, j, 64);
                    int    ni0 = __shfl_xor(i0, j, 64);
                    int    ni1 = __shfl_xor(i1, j, 64);
                    bool lower = ((l & j) == 0);
                    bool up0 = ((l & k) == 0);
                    bool up1 = (((l + 64) & k) == 0);
                    bool bm0 = (v0 > nv0) || (v0 == nv0 && i0 < ni0);
                    bool bm1 = (v1 > nv1) || (v1 == nv1 && i1 < ni1);
                    bool keep0 = lower ? (up0 == bm0) : (up0 != bm0);
                    bool keep1 = lower ? (up1 == bm1) : (up1 != bm1);
                    if (!keep0) { v0 = nv0; i0 = ni0; }
                    if (!keep1) { v1 = nv1; i1 = ni1; }
                }
            }
        }
        s_v64[l] = v0; s_v64[l + 64] = v1;
        s_ki[l]  = i0; s_ki[l + 64]  = i1;
    }
    __syncthreads();

    // ---------------- phase 4: f64 top-k cut + top-p + log-softmax ----------------
    if (tid == 0) {
        int kk = k50c;
        int Kkept;
        if (kk <= 50) Kkept = kk;
        else {
            double kth64 = s_v64[49];
            Kkept = 50;
            while (Kkept < kk && s_v64[Kkept] == kth64) ++Kkept;
        }
        s_Kk = Kkept;
    }
    __syncthreads();
    const int Kk = s_Kk;
    const double mx = s_v64[0];
    if (tid < Kk) s_e64[tid] = exp(s_v64[tid] - mx);   // parallel f64 exp
    __syncthreads();
    if (tid == 0) {
        double D = 0.0;                       // same serial order as before
        #pragma unroll 1
        for (int i = 0; i < Kk; ++i) D += s_e64[i];
        double c = 0.0;
        int Kp = 0;
        #pragma unroll 1
        for (int i = 0; i < Kk; ++i) {
            bool keep = (i == 0) || (c <= 0.9);
            c += s_e64[i] / D;
            if (keep) Kp = i + 1; else break;
        }
        double D2 = 0.0;
        #pragma unroll 1
        for (int i = 0; i < Kp; ++i) D2 += s_e64[i];
        double lse = log(D2);
        s_lse = lse;
        s_rc = (float)((-1e9 - mx) - lse);
        s_kp = Kp;
    }
    __syncthreads();
    if (tid < s_kp) s_kof[tid] = (float)((s_v64[tid] - mx) - s_lse);

    // ---------------- phase 5: unconditional fill, drain, scatter ----------------
    const float rc = s_rc;
    {
        const int omis   = (int)(((size_t)orow >> 2) & 3);
        const int ohead  = (4 - omis) & 3;
        const int onq    = (VV - ohead) >> 2;
        const int ottail = ohead + (onq << 2);
        float4* o4 = reinterpret_cast<float4*>(orow + ohead);
        const float4 rc4 = make_float4(rc, rc, rc, rc);
        for (int t = tid; t < ohead; t += NT) orow[t] = rc;
        for (int q = tid; q < onq; q += NT) o4[q] = rc4;
        for (int t = ottail + tid; t < VV; t += NT) orow[t] = rc;
    }
    __syncthreads();   // vmcnt(0) drain before barrier -> scatter ordered after fill
    if (tid < s_kp) orow[s_ki[tid]] = s_kof[tid];
}

extern "C" void kernel_launch(void* const* d_in, const int* in_sizes, int n_in,
                              void* d_out, int out_size, void* d_ws, size_t ws_size,
                              hipStream_t stream) {
    const float* logits = (const float*)d_in[0];
    const int*   prev   = (const int*)d_in[1];
    float*       out    = (float*)d_out;
    dim3 grid(BB * SS), block(NT);
    hipLaunchKernelGGL(sch_kernel, grid, block, 0, stream, logits, prev, out);
}

// Round 7
// 99.396 us; speedup vs baseline: 1.7401x; 1.1373x over previous
//
#include <hip/hip_runtime.h>
#include <cstdint>
#include <cfloat>
#include <math.h>

// Problem constants (match reference)
#define BB 16
#define SS 64
#define VV 50257
#define PP 64

#define NT 512          // threads per block (8 waves; 4 blocks/CU -> 32 waves/CU)
#define BINS 2048       // key histogram bins (top 11 bits of ordered key)
#define CAP 1536        // candidate buffer capacity
#define BMW 1572        // bitmap words: ceil(50257/32)=1571 (+1 pad)
#define KCAP 128        // kept (top-k survivors) capacity
#define BCAP 512        // kth-bin member list capacity
#define TRAW 6.0f       // raw-domain candidate threshold (= 7.5 scaled * 0.8)

typedef float f32x4 __attribute__((ext_vector_type(4)));

// monotone float->uint key (increasing)
__device__ __forceinline__ uint32_t fkey(float f) {
    uint32_t u = __float_as_uint(f);
    return u ^ ((uint32_t)((int32_t)u >> 31) | 0x80000000u);
}
__device__ __forceinline__ float key2f(uint32_t u) {
    uint32_t b = (u & 0x80000000u) ? (u ^ 0x80000000u) : ~u;
    return __uint_as_float(b);
}

__global__ __launch_bounds__(NT)
void sch_kernel(const float* __restrict__ logits,
                const int* __restrict__ prev,
                float* __restrict__ out)
{
    const int r   = blockIdx.x;            // row in [0, B*S)
    const int b   = r / SS;
    const int s   = r % SS;
    const int tid = threadIdx.x;
    const float* row  = logits + (size_t)r * VV;
    float*       orow = out    + (size_t)r * VV;

    __shared__ uint32_t s_bm[BMW];
    __shared__ float    s_cv[CAP];    // candidate value, PRE-TEMPERATURE domain
    __shared__ int      s_ci[CAP];
    __shared__ uint32_t s_hist[BINS];
    __shared__ uint32_t s_scan[16];   // 8 wave totals + 8 wave prefixes
    __shared__ int      s_ptok[PP];
    __shared__ float    s_ppen[PP];   // f32 pre-temp penalized value (selection only)
    __shared__ float    s_praw[PP];   // raw f32 logit of penalized token (this batch)
    __shared__ int      s_pneg[PP];   // all_neg flag
    __shared__ float    s_binv[BCAP];
    __shared__ double   s_v64[KCAP];  // f64 decision values of kept candidates
    __shared__ double   s_e64[KCAP];  // f64 exp(v-mx), parallel-computed
    __shared__ int      s_ki[KCAP];
    __shared__ float    s_kof[KCAP];  // final f32 log-probs (sorted order)
    __shared__ int    s_cnt, s_cntinv, s_b50, s_need, s_cntb, s_k50, s_kp, s_Kk;
    __shared__ float  s_kth, s_rc;
    __shared__ double s_lse;

    // ---------------- phase 0: repetition-penalty setup (parallel gather) ----------
    for (int i = tid; i < BMW; i += NT) s_bm[i] = 0u;
    if (tid < PP) s_pneg[tid] = 1;
    if (tid == 0) { s_cnt = 0; s_cntinv = 0; }
    __syncthreads();
    // 64 tokens x 16 batches = 1024 independent scattered loads over 512 threads
    for (int pair = tid; pair < PP * BB; pair += NT) {
        int ti = pair & (PP - 1);
        int b2 = pair >> 6;
        int tok = prev[s * PP + ti];
        float g = logits[((size_t)b2 * SS + s) * (size_t)VV + tok];
        if (g >= 0.f) atomicAnd(&s_pneg[ti], 0);
        if (b2 == b) { s_praw[ti] = g; s_ptok[ti] = tok; }
    }
    __syncthreads();
    if (tid < PP) {
        float gown = s_praw[tid];
        float pen = s_pneg[tid] ? (gown * 1.2f) : (gown / 1.2f);
        s_ppen[tid] = pen;                 // pre-temp domain (selection only)
        int tok = s_ptok[tid];
        atomicOr(&s_bm[tok >> 5], 1u << (tok & 31));
    }
    __syncthreads();

    // ---------------- streaming geometry ----------------
    const int mis   = (int)(((size_t)row >> 2) & 3);
    const int head  = (4 - mis) & 3;
    const int nq    = (VV - head) >> 2;
    const int ttail = head + (nq << 2);
    const float4* p4 = reinterpret_cast<const float4*>(row + head);

    auto kbit = [&](int t) -> uint32_t {
        return (s_bm[t >> 5] >> (t & 31)) & 1u;
    };
    auto addRaw = [&](int t, float raw) {
        if (raw >= TRAW) {
            int pos = atomicAdd(&s_cnt, 1);
            if (pos < CAP) { s_cv[pos] = raw; s_ci[pos] = t; }
        }
    };
    // hot read stream: NO LDS on the fast path, 4-deep unrolled for MLP
    auto streamFast = [&]() {
        for (int t = tid; t < head; t += NT) addRaw(t, row[t]);
        int base = 0;
        for (; base + 4 * NT <= nq; base += 4 * NT) {
            float4 f[4];
            #pragma unroll
            for (int u = 0; u < 4; ++u) f[u] = p4[base + tid + u * NT];
            #pragma unroll
            for (int u = 0; u < 4; ++u) {
                int t = head + ((base + tid + u * NT) << 2);
                addRaw(t + 0, f[u].x);
                addRaw(t + 1, f[u].y);
                addRaw(t + 2, f[u].z);
                addRaw(t + 3, f[u].w);
            }
        }
        for (int q = base + tid; q < nq; q += NT) {
            float4 f = p4[q];
            int t = head + (q << 2);
            addRaw(t + 0, f.x);
            addRaw(t + 1, f.y);
            addRaw(t + 2, f.z);
            addRaw(t + 3, f.w);
        }
        for (int t = ttail + tid; t < VV; t += NT) addRaw(t, row[t]);
    };
    // full path (rare fallback): per-element penalty substitution, pre-temp domain
    auto procFull = [&](int t, float raw, bool doHist, float thr) {
        float v = raw;
        if (kbit(t)) {
            #pragma unroll 1
            for (int j = 0; j < PP; ++j)
                if (s_ptok[j] == t) { v = s_ppen[j]; break; }
        }
        if (!doHist) {
            if (v >= thr) {
                int pos = atomicAdd(&s_cnt, 1);
                if (pos < CAP) { s_cv[pos] = v; s_ci[pos] = t; }
            }
        } else {
            atomicAdd(&s_hist[fkey(v) >> 21], 1u);
        }
    };
    auto streamFull = [&](bool doHist, float thr) {
        for (int t = tid; t < head; t += NT) procFull(t, row[t], doHist, thr);
        for (int q = tid; q < nq; q += NT) {
            float4 f = p4[q];
            int t = head + (q << 2);
            procFull(t + 0, f.x, doHist, thr);
            procFull(t + 1, f.y, doHist, thr);
            procFull(t + 2, f.z, doHist, thr);
            procFull(t + 3, f.w, doHist, thr);
        }
        for (int t = ttail + tid; t < VV; t += NT) procFull(t, row[t], doHist, thr);
    };
    // suffix "find bin crossing target from top", shfl-scan version (2 barriers)
    auto findB50 = [&](int target) {
        __syncthreads();                     // histogram complete
        const int per = BINS / NT;           // 4 bins per thread
        int base = tid * per;
        uint32_t loc = 0;
        #pragma unroll
        for (int k2 = 0; k2 < per; ++k2) loc += s_hist[base + k2];
        uint32_t incl = loc;                 // wave-level inclusive scan
        #pragma unroll
        for (int off = 1; off < 64; off <<= 1) {
            uint32_t u = (uint32_t)__shfl_up((int)incl, off, 64);
            if ((tid & 63) >= off) incl += u;
        }
        int wid = tid >> 6;
        if ((tid & 63) == 63) s_scan[wid] = incl;
        __syncthreads();
        if (tid < 8) {                       // tiny exclusive wave-prefix
            uint32_t p = 0;
            for (int w = 0; w < tid; ++w) p += s_scan[w];
            s_scan[8 + tid] = p;
        }
        __syncthreads();
        uint32_t pre_incl = s_scan[8 + wid] + incl;
        uint32_t total    = s_scan[8 + 7] + s_scan[7];
        uint32_t run = total - pre_incl;     // sum of bins above my top bin
        for (int k2 = per - 1; k2 >= 0; --k2) {
            uint32_t h = s_hist[base + k2];
            uint32_t run2 = run + h;
            if (run < (uint32_t)target && run2 >= (uint32_t)target) {
                s_b50 = base + k2;
                s_need = target - (int)run;
            }
            run = run2;
        }
        __syncthreads();
    };
    auto doFallback = [&]() {
        for (int i = tid; i < BINS; i += NT) s_hist[i] = 0u;
        __syncthreads();
        streamFull(true, 0.f);
        findB50(50);
        float thrF = key2f((uint32_t)s_b50 << 21);
        if (tid == 0) s_cnt = 0;
        __syncthreads();
        streamFull(false, thrF);
        __syncthreads();
    };
    auto computeKth = [&]() {
        for (int i = tid; i < BINS; i += NT) s_hist[i] = 0u;
        if (tid == 0) { s_cntb = 0; s_kth = -FLT_MAX; }
        __syncthreads();
        int cc = min(s_cnt, CAP);
        for (int i = tid; i < cc; i += NT)
            atomicAdd(&s_hist[fkey(s_cv[i]) >> 21], 1u);
        findB50(50);
        int b50 = s_b50, need = s_need;
        for (int i = tid; i < cc; i += NT) {
            if ((int)(fkey(s_cv[i]) >> 21) == b50) {
                int p = atomicAdd(&s_cntb, 1);
                if (p < BCAP) s_binv[p] = s_cv[i];
            }
        }
        __syncthreads();
        int cb = min(s_cntb, BCAP);
        for (int i = tid; i < cb; i += NT) {    // rank-count (grid-stride)
            float vi = s_binv[i];
            int gt = 0, ge = 0;
            for (int j = 0; j < cb; ++j) {
                float vj = s_binv[j];
                gt += (vj > vi);
                ge += (vj >= vi);
            }
            if (gt < need && ge >= need) s_kth = vi;   // benign race: same value
        }
        __syncthreads();
    };

    // ---------------- phase 1: collect candidates (1 global read) ----------------
    streamFast();
    __syncthreads();
    const int cntRaw = min(s_cnt, CAP);
    for (int i = tid; i < cntRaw; i += NT) {     // invalidate penalized raw entries
        if (kbit(s_ci[i])) {
            s_cv[i] = -FLT_MAX;
            atomicAdd(&s_cntinv, 1);
        }
    }
    __syncthreads();
    if (tid < PP) {                              // inject pen values (dedupe)
        int tok = s_ptok[tid];
        bool first = true;
        for (int j = 0; j < tid; ++j)
            if (s_ptok[j] == tok) { first = false; break; }
        if (first) {
            int pos = atomicAdd(&s_cnt, 1);
            if (pos < CAP) { s_cv[pos] = s_ppen[tid]; s_ci[pos] = tok; }
        }
    }
    __syncthreads();
    bool fellback = false;
    {
        bool okc = (s_cnt <= CAP) && ((cntRaw - s_cntinv) >= 50);
        if (!okc) { doFallback(); fellback = true; }
    }

    // ---------------- phase 2: f32 kth among candidates ----------------
    computeKth();
    if (!fellback && (s_kth - 1e-4f < TRAW)) {   // margin guard: superset unproven
        doFallback();
        computeKth();
    }
    if (tid == 0) s_k50 = 0;
    __syncthreads();
    const float kth = s_kth;

    // ---------------- phase 3: gather kept (margin below kth32), f64 values ----------
    const float gthr = kth - 1e-4f;
    const int cntc = min(s_cnt, CAP);
    for (int i = tid; i < cntc; i += NT) {
        if (s_cv[i] >= gthr) {
            int p = atomicAdd(&s_k50, 1);
            if (p < KCAP) {
                int tok = s_ci[i];
                double v64;
                if (kbit(tok)) {                   // penalized: exact f64 recompute
                    int pj = 0;
                    #pragma unroll 1
                    for (int j = 0; j < PP; ++j)
                        if (s_ptok[j] == tok) { pj = j; break; }
                    double g = (double)s_praw[pj];
                    double pen = s_pneg[pj] ? (g * 1.2) : (g / 1.2);
                    v64 = pen / 0.8;
                } else {
                    v64 = (double)s_cv[i] / 0.8;   // raw rode along in s_cv
                }
                s_v64[p] = v64;
                s_ki[p]  = tok;
            }
        }
    }
    __syncthreads();
    const int k50c = min(s_k50, KCAP);
    for (int i = k50c + tid; i < KCAP; i += NT) {
        s_v64[i] = -1e300;
        s_ki[i]  = (1 << 30) + i;
    }
    __syncthreads();

    // ---------------- single-wave register bitonic sort (128 slots, 0 barriers) ----
    // lane l holds slots l and l+64; descending v64, tie -> ascending token idx.
    if (tid < 64) {
        int l = tid;
        double v0 = s_v64[l],    v1 = s_v64[l + 64];
        int    i0 = s_ki[l],     i1 = s_ki[l + 64];
        for (int k = 2; k <= KCAP; k <<= 1) {
            for (int j = k >> 1; j > 0; j >>= 1) {
                if (j >= 64) {          // j==64 (k==128): in-lane slot pair, up=true
                    bool before = (v0 > v1) || (v0 == v1 && i0 < i1);
                    if (!before) {
                        double tv = v0; v0 = v1; v1 = tv;
                        int    ti = i0; i0 = i1; i1 = ti;
                    }
                } else {
                    double nv0 = __shfl_xor(v0, j, 64);
                    double nv1 = __shfl_xor(v1, j, 64);
                    int    ni0 = __shfl_xor(i0, j, 64);
                    int    ni1 = __shfl_xor(i1, j, 64);
                    bool lower = ((l & j) == 0);
                    bool up0 = ((l & k) == 0);
                    bool up1 = (((l + 64) & k) == 0);
                    bool bm0 = (v0 > nv0) || (v0 == nv0 && i0 < ni0);
                    bool bm1 = (v1 > nv1) || (v1 == nv1 && i1 < ni1);
                    bool keep0 = lower ? (up0 == bm0) : (up0 != bm0);
                    bool keep1 = lower ? (up1 == bm1) : (up1 != bm1);
                    if (!keep0) { v0 = nv0; i0 = ni0; }
                    if (!keep1) { v1 = nv1; i1 = ni1; }
                }
            }
        }
        s_v64[l] = v0; s_v64[l + 64] = v1;
        s_ki[l]  = i0; s_ki[l + 64]  = i1;
    }
    __syncthreads();

    // ---------------- phase 4: f64 top-k cut + top-p + log-softmax ----------------
    if (tid == 0) {
        int kk = k50c;
        int Kkept;
        if (kk <= 50) Kkept = kk;
        else {
            double kth64 = s_v64[49];
            Kkept = 50;
            while (Kkept < kk && s_v64[Kkept] == kth64) ++Kkept;
        }
        s_Kk = Kkept;
    }
    __syncthreads();
    const int Kk = s_Kk;
    const double mx = s_v64[0];
    if (tid < Kk) s_e64[tid] = exp(s_v64[tid] - mx);   // parallel f64 exp
    __syncthreads();
    if (tid == 0) {
        double D = 0.0;                       // same serial order as before
        #pragma unroll 1
        for (int i = 0; i < Kk; ++i) D += s_e64[i];
        double c = 0.0;
        int Kp = 0;
        #pragma unroll 1
        for (int i = 0; i < Kk; ++i) {
            bool keep = (i == 0) || (c <= 0.9);
            c += s_e64[i] / D;
            if (keep) Kp = i + 1; else break;
        }
        double D2 = 0.0;
        #pragma unroll 1
        for (int i = 0; i < Kp; ++i) D2 += s_e64[i];
        double lse = log(D2);
        s_lse = lse;
        s_rc = (float)((-1e9 - mx) - lse);
        s_kp = Kp;
    }
    __syncthreads();
    if (tid < s_kp) s_kof[tid] = (float)((s_v64[tid] - mx) - s_lse);

    // ---------------- phase 5: NONTEMPORAL fill, drain, scatter ----------------
    // nt stores bypass L2/L3 allocation: keeps Infinity Cache serving the input
    // stream instead of absorbing 203 MB of write-allocate + dirty evictions.
    const float rc = s_rc;
    {
        const int omis   = (int)(((size_t)orow >> 2) & 3);
        const int ohead  = (4 - omis) & 3;
        const int onq    = (VV - ohead) >> 2;
        const int ottail = ohead + (onq << 2);
        f32x4* o4 = reinterpret_cast<f32x4*>(orow + ohead);
        f32x4 rc4; rc4.x = rc; rc4.y = rc; rc4.z = rc; rc4.w = rc;
        for (int t = tid; t < ohead; t += NT)
            __builtin_nontemporal_store(rc, &orow[t]);
        for (int q = tid; q < onq; q += NT)
            __builtin_nontemporal_store(rc4, &o4[q]);
        for (int t = ottail + tid; t < VV; t += NT)
            __builtin_nontemporal_store(rc, &orow[t]);
    }
    __syncthreads();   // vmcnt(0) drain before barrier -> scatter ordered after fill
    if (tid < s_kp) orow[s_ki[tid]] = s_kof[tid];
}

extern "C" void kernel_launch(void* const* d_in, const int* in_sizes, int n_in,
                              void* d_out, int out_size, void* d_ws, size_t ws_size,
                              hipStream_t stream) {
    const float* logits = (const float*)d_in[0];
    const int*   prev   = (const int*)d_in[1];
    float*       out    = (float*)d_out;
    dim3 grid(BB * SS), block(NT);
    hipLaunchKernelGGL(sch_kernel, grid, block, 0, stream, logits, prev, out);
}